// Round 14
// baseline (427.536 us; speedup 1.0000x reference)
//
#include <hip/hip_runtime.h>

#define L 21
#define NVOX 4096
#define ITERS 5
#define NU 210      // monomials of degree <= 4 in 6 vars
#define UPAD 256    // padded rows (210..255 are zero)
#define NBLK 256
#define TPB 1024
#define READY_MAGIC 0x13579BDF

typedef float f4 __attribute__((ext_vector_type(4)));

// ---- coherence helpers -----------------------------------------------------
// st_cg: scalar store straight to LLC (sc1) — globally visible, no L2 residue.
// nt4/nt1: non-temporal loads — never allocate in L1/L2, so a buffer that is
// ONLY ever read non-temporally can never serve a stale cached copy.
// Immutable-after-setup data (Phi, W1/W2, cu, nsp) is written st_cg once and
// read with normal cached loads: L2s are invalidated at dispatch start, so
// the first normal read fetches the fresh LLC copy and may cache it freely.
__device__ __forceinline__ void st_cg(float* p, float v) {
    __hip_atomic_store(p, v, __ATOMIC_RELAXED, __HIP_MEMORY_SCOPE_AGENT);
}
__device__ __forceinline__ f4 nt4(const float* p) {
    return __builtin_nontemporal_load((const f4*)p);
}
__device__ __forceinline__ float nt1(const float* p) {
    return __builtin_nontemporal_load(p);
}

// Fence-free grid barrier (R10-verified): __syncthreads drains this block's
// vmem (sc1 stores are then at LLC); arrive/poll are relaxed agent atomics
// (LLC); workgroup fences are waitcnt-only — NO buffer_wbl2 / buffer_inv.
__device__ __forceinline__ void gbar(int* cnt) {
    __builtin_amdgcn_fence(__ATOMIC_RELEASE, "workgroup");
    __syncthreads();
    if (threadIdx.x == 0) {
        __hip_atomic_fetch_add(cnt, 1, __ATOMIC_RELAXED, __HIP_MEMORY_SCOPE_AGENT);
        while (__hip_atomic_load(cnt, __ATOMIC_RELAXED, __HIP_MEMORY_SCOPE_AGENT) < NBLK)
            __builtin_amdgcn_s_sleep(1);
        __builtin_amdgcn_fence(__ATOMIC_ACQUIRE, "workgroup");
    }
    __syncthreads();
}

struct SpSh { float buf[NVOX]; float tmp[NVOX]; };            // 32 KB
struct P3Sh { float sA[L * UPAD]; float sN[UPAD]; float sw1[L * L]; }; // ~24 KB
union SharedU { SpSh sp; P3Sh p3; };

__global__ __launch_bounds__(TPB, 1) void crf_fused(
    const float* __restrict__ img, const float* __restrict__ logits,
    const float* __restrict__ Wsp, const float* __restrict__ Wbi,
    const float* __restrict__ Wc, float* __restrict__ out,
    int* bar, float* __restrict__ Phi, float* __restrict__ nsp,
    float* __restrict__ q, float* __restrict__ spv, float* __restrict__ A2,
    float* __restrict__ cu, float* __restrict__ W1, float* __restrict__ W2)
{
    __shared__ SharedU su;
    const int tid = threadIdx.x;
    const int bid = blockIdx.x;
    const int lane = tid & 63;
    const int wv = tid >> 6;           // wave 0..15
    const float garr[5] = {1.0f, 0.60653066f, 0.13533528f,
                           0.011108997f, 3.3546263e-4f};

    // ---- ready-gate (poison-tolerant, relaxed polls) ----
    if (bid == 0 && tid == 0) {
        for (int k = 0; k < 12; k++)
            __hip_atomic_store(bar + k * 16, 0, __ATOMIC_RELAXED, __HIP_MEMORY_SCOPE_AGENT);
        __hip_atomic_store(bar + 255, READY_MAGIC, __ATOMIC_RELAXED, __HIP_MEMORY_SCOPE_AGENT);
    }
    if (tid == 0) {
        while (__hip_atomic_load(bar + 255, __ATOMIC_RELAXED, __HIP_MEMORY_SCOPE_AGENT) != READY_MAGIC)
            __builtin_amdgcn_s_sleep(1);
        __builtin_amdgcn_fence(__ATOMIC_ACQUIRE, "workgroup");
    }
    __syncthreads();
    int bk = 0;

    // ================= Phase AB: Phi + nsp + q0 + tables =================
    {
        const int i = bid * 16 + wv;   // one voxel per wave
        int z = i >> 8, yy = (i >> 4) & 15, xx = i & 15;
        const float ia = 1.0f / 67.0f, ib = 1.0f / 3.0f;
        float f[6];
        f[0] = (float)z * ia; f[1] = (float)yy * ia; f[2] = (float)xx * ia;
        f[3] = img[i] * ib; f[4] = img[NVOX + i] * ib; f[5] = img[2 * NVOX + i] * ib;
        float pw[6][5];
#pragma unroll
        for (int c = 0; c < 6; c++) {
            pw[c][0] = 1.f;
#pragma unroll
            for (int k = 1; k < 5; k++) pw[c][k] = pw[c][k - 1] * f[c];
        }
        float hsv = 0.5f * (f[0]*f[0] + f[1]*f[1] + f[2]*f[2] +
                            f[3]*f[3] + f[4]*f[4] + f[5]*f[5]);
        float e0 = __expf(-hsv);
        int u = 0;
        for (int a0 = 0; a0 <= 4; a0++)
        for (int a1 = 0; a1 <= 4 - a0; a1++)
        for (int a2 = 0; a2 <= 4 - a0 - a1; a2++)
        for (int a3 = 0; a3 <= 4 - a0 - a1 - a2; a3++)
        for (int a4 = 0; a4 <= 4 - a0 - a1 - a2 - a3; a4++)
        for (int a5 = 0; a5 <= 4 - a0 - a1 - a2 - a3 - a4; a5++) {
            if ((u >> 2) == lane)
                st_cg(&Phi[(size_t)u * NVOX + i],
                      e0 * pw[0][a0] * pw[1][a1] * pw[2][a2] * pw[3][a3] * pw[4][a4] * pw[5][a5]);
            u++;
        }
        for (int uz = NU; uz < UPAD; uz++)
            if ((uz >> 2) == lane) st_cg(&Phi[(size_t)uz * NVOX + i], 0.f);
        if (lane == 0) {
            float hz = 0.f, hy = 0.f, hx = 0.f;
            for (int t = 0; t < 16; t++) {
                float dz = (float)(z - t), dy = (float)(yy - t), dx = (float)(xx - t);
                hz += __expf(-0.5f * dz * dz);
                hy += __expf(-0.5f * dy * dy);
                hx += __expf(-0.5f * dx * dx);
            }
            st_cg(&nsp[i], hz * hy * hx);
        }
        // q0 = softmax(logits) per voxel, in-wave
        {
            float lg = (lane < L) ? logits[lane * NVOX + i] : -1e30f;
            float mx = lg;
#pragma unroll
            for (int off = 32; off >= 1; off >>= 1) mx = fmaxf(mx, __shfl_xor(mx, off));
            float ex = (lane < L) ? __expf(lg - mx) : 0.f;
            float sm = ex;
#pragma unroll
            for (int off = 32; off >= 1; off >>= 1) sm += __shfl_xor(sm, off);
            if (lane < L) st_cg(&q[lane * NVOX + i], ex / sm);
        }
        if (bid == 0 && tid < 256) {   // cu table
            const float invf[5] = {1.f, 1.f, 0.5f, 1.f / 6.f, 1.f / 24.f};
            float mine = 0.f;
            int v = 0;
            for (int a0 = 0; a0 <= 4; a0++)
            for (int a1 = 0; a1 <= 4 - a0; a1++)
            for (int a2 = 0; a2 <= 4 - a0 - a1; a2++)
            for (int a3 = 0; a3 <= 4 - a0 - a1 - a2; a3++)
            for (int a4 = 0; a4 <= 4 - a0 - a1 - a2 - a3; a4++)
            for (int a5 = 0; a5 <= 4 - a0 - a1 - a2 - a3 - a4; a5++) {
                if (v == tid)
                    mine = invf[a0] * invf[a1] * invf[a2] * invf[a3] * invf[a4] * invf[a5];
                v++;
            }
            st_cg(&cu[tid], mine);
        }
        if (bid == 1) {                // W1 = Wc@Wsp, W2 = Wc@Wbi
            for (int e = tid; e < L * L; e += TPB) {
                int r = e / L, c = e % L;
                float s1 = 0.f, s2 = 0.f;
                for (int k = 0; k < L; k++) {
                    float wc = Wc[r * L + k];
                    s1 = fmaf(wc, Wsp[k * L + c], s1);
                    s2 = fmaf(wc, Wbi[k * L + c], s2);
                }
                st_cg(&W1[e], s1); st_cg(&W2[e], s2);
            }
        }
        if (bid == 2)                  // zero both A2 buffers
            for (int e = tid; e < 2 * 22 * UPAD; e += TPB) st_cg(&A2[e], 0.f);
    }
    gbar(bar + (bk++) * 16);

    for (int it = 0; it < ITERS; it++) {
        float* A2cur  = A2 + (it & 1) * 22 * UPAD;
        float* A2next = A2 + ((it + 1) & 1) * 22 * UPAD;
        const int last = (it == ITERS - 1);

        // ===== P2: g1 (blocks 0..209) | spatial (blocks 210..230) =====
        if (bid < NU) {
            const int u = bid;
            const int i0 = wv * 256;
            f4 pv = *(const f4*)(Phi + (size_t)u * NVOX + i0 + lane * 4);  // cached
            float acc[22];
            acc[21] = pv.x + pv.y + pv.z + pv.w;
#pragma unroll
            for (int m = 0; m < L; m++) {
                f4 qv = nt4(q + m * NVOX + i0 + lane * 4);
                acc[m] = fmaf(qv.x, pv.x, fmaf(qv.y, pv.y,
                         fmaf(qv.z, pv.z, qv.w * pv.w)));
            }
#pragma unroll
            for (int off = 32; off >= 1; off >>= 1)
#pragma unroll
                for (int m = 0; m < 22; m++)
                    acc[m] += __shfl_xor(acc[m], off);
            if (lane < 22) {
                float val;
                if (lane < L) {
                    float dot = 0.f;
#pragma unroll
                    for (int m = 0; m < L; m++)
                        dot = fmaf(W2[lane * L + m], acc[m], dot);
                    val = cu[u] * dot;
                } else {
                    val = cu[u] * acc[21];
                }
                atomicAdd(&A2cur[lane * UPAD + u], val);
            }
        } else if (bid < NU + L) {
            const int l = bid - NU;
            for (int k = 0; k < 4; k++)
                su.sp.buf[tid + 1024 * k] = nt1(&q[l * NVOX + tid + 1024 * k]);
            __syncthreads();
            for (int k = 0; k < 4; k++) {
                int idx = tid + 1024 * k;
                int x = idx & 15, base = idx & ~15;
                float s = 0.f;
#pragma unroll
                for (int dt = -4; dt <= 4; dt++) {
                    int t = x + dt, ad = dt < 0 ? -dt : dt;
                    if (t >= 0 && t < 16) s = fmaf(garr[ad], su.sp.buf[base + t], s);
                }
                su.sp.tmp[idx] = s;
            }
            __syncthreads();
            for (int k = 0; k < 4; k++) {
                int idx = tid + 1024 * k;
                int y = (idx >> 4) & 15, base = idx & ~(15 << 4);
                float s = 0.f;
#pragma unroll
                for (int dt = -4; dt <= 4; dt++) {
                    int t = y + dt, ad = dt < 0 ? -dt : dt;
                    if (t >= 0 && t < 16) s = fmaf(garr[ad], su.sp.tmp[base + (t << 4)], s);
                }
                su.sp.buf[idx] = s;
            }
            __syncthreads();
            for (int k = 0; k < 4; k++) {
                int idx = tid + 1024 * k;
                int z = idx >> 8, base = idx & 255;
                float s = 0.f;
#pragma unroll
                for (int dt = -4; dt <= 4; dt++) {
                    int t = z + dt, ad = dt < 0 ? -dt : dt;
                    if (t >= 0 && t < 16) s = fmaf(garr[ad], su.sp.buf[base + (t << 8)], s);
                }
                st_cg(&spv[l * NVOX + idx], s);
            }
        }
        gbar(bar + (bk++) * 16);

        // ===== P3: g2 + combine + softmax (wave-per-voxel, no red LDS) =====
        if (bid == 3)    // zero next iteration's A2 buffer
            for (int e = tid; e < 22 * UPAD; e += TPB) st_cg(&A2next[e], 0.f);
        for (int e = tid; e < (L * UPAD) / 4; e += TPB)
            ((f4*)su.p3.sA)[e] = nt4(A2cur + 4 * e);
        if (tid < UPAD / 4)
            ((f4*)su.p3.sN)[tid] = nt4(A2cur + L * UPAD + 4 * tid);
        for (int e = tid; e < L * L; e += TPB) su.p3.sw1[e] = W1[e];
        __syncthreads();
        {
            const int i = bid * 16 + wv;
            float b[22];
#pragma unroll
            for (int m = 0; m < 22; m++) b[m] = 0.f;
#pragma unroll
            for (int j = 0; j < 4; j++) {
                int u = lane + j * 64;            // bank-conflict-free LDS layout
                float ph = Phi[(size_t)u * NVOX + i];   // cached (16 vox = 1 line)
#pragma unroll
                for (int m = 0; m < L; m++)
                    b[m] = fmaf(su.p3.sA[m * UPAD + u], ph, b[m]);
                b[21] = fmaf(su.p3.sN[u], ph, b[21]);
            }
#pragma unroll
            for (int off = 32; off >= 1; off >>= 1)
#pragma unroll
                for (int m = 0; m < 22; m++)
                    b[m] += __shfl_xor(b[m], off);
            float rsp = 1.f / nsp[i];
            float spn = (lane < L) ? nt1(&spv[lane * NVOX + i]) * rsp : 0.f;
            float rbi = 1.f / b[21];
            int l2 = (lane < L) ? lane : 0;
            float r = b[l2] * rbi;
#pragma unroll
            for (int m = 0; m < L; m++)
                r = fmaf(su.p3.sw1[l2 * L + m], __shfl(spn, m), r);
            r += logits[l2 * NVOX + i];
            if (last) {
                if (lane < L) out[lane * NVOX + i] = r;
            } else {
                float v = (lane < L) ? r : -1e30f;
                float mx = v;
#pragma unroll
                for (int off = 32; off >= 1; off >>= 1) mx = fmaxf(mx, __shfl_xor(mx, off));
                float ex = (lane < L) ? __expf(v - mx) : 0.f;
                float sm = ex;
#pragma unroll
                for (int off = 32; off >= 1; off >>= 1) sm += __shfl_xor(sm, off);
                if (lane < L) st_cg(&q[lane * NVOX + i], ex / sm);
            }
        }
        if (!last) gbar(bar + (bk++) * 16);
    }

    // cleanup so replay re-inits safely (stream order protects us)
    if (bid == 0 && tid == 0)
        __hip_atomic_store(bar + 255, 0, __ATOMIC_RELAXED, __HIP_MEMORY_SCOPE_AGENT);
}

extern "C" void kernel_launch(void* const* d_in, const int* in_sizes, int n_in,
                              void* d_out, int out_size, void* d_ws, size_t ws_size,
                              hipStream_t stream) {
    const float* image  = (const float*)d_in[0];
    const float* logits = (const float*)d_in[1];
    const float* Wsp    = (const float*)d_in[2];
    const float* Wbi    = (const float*)d_in[3];
    const float* Wc     = (const float*)d_in[4];
    float* out = (float*)d_out;

    char* ws = (char*)d_ws;
    int*   bar = (int*)ws;   ws += 1024;
    float* Phi = (float*)ws; ws += (size_t)UPAD * NVOX * sizeof(float);    // 4 MB
    float* nsp = (float*)ws; ws += (size_t)NVOX * sizeof(float);
    float* q   = (float*)ws; ws += (size_t)L * NVOX * sizeof(float);
    float* spv = (float*)ws; ws += (size_t)L * NVOX * sizeof(float);
    float* A2  = (float*)ws; ws += (size_t)2 * 22 * UPAD * sizeof(float);  // double buffer
    float* cu  = (float*)ws; ws += (size_t)256 * sizeof(float);
    float* W1  = (float*)ws; ws += (size_t)L * L * sizeof(float);
    float* W2  = (float*)ws; ws += (size_t)L * L * sizeof(float);

    crf_fused<<<NBLK, TPB, 0, stream>>>(image, logits, Wsp, Wbi, Wc, out,
                                        bar, Phi, nsp, q, spv, A2, cu, W1, W2);
}